// Round 9
// baseline (108.301 us; speedup 1.0000x reference)
//
#include <hip/hip_runtime.h>

#define Hd 256
#define NPSd 48
#define Sd 64
#define Nd (Sd*NPSd)

// LDS-only barrier: no vmcnt drain, in-flight global loads survive it.
__device__ __forceinline__ void barrier_lds() {
  asm volatile("s_waitcnt lgkmcnt(0)" ::: "memory");
  __builtin_amdgcn_s_barrier();
}

// ---------------------------------------------------------------------------
// One block = ONE agent row (grid 3072, 128 threads = 2 waves, 24 waves/CU).
//  phase 1: pt = W2*t+b2  (waves split a-range; 16-a lane pattern, q-quarters)
//  phase 2: v = W1^T*pt   (thread owns h-pair, coalesced W1, pt broadcast)
//  phase 3: wave w scores+aggregates j = w*24 .. w*24+23, 4-row chunks,
//           A/B 2-deep register pipeline, ZERO barriers, free-running waves.
//  tail:    2-way cross-wave combine, one LDS barrier, write row.
__global__ __launch_bounds__(128, 6) void fused_kernel(
    const float* __restrict__ spatial,
    const float* __restrict__ temporal,
    const float* __restrict__ W1_w, const float* __restrict__ W1_b,
    const float* __restrict__ W2_w, const float* __restrict__ W2_b,
    const int* __restrict__ ts_mask,
    float* __restrict__ out) {
  __shared__ float t_lds[4][68];   // t in h-quarters, padded (bank spread)
  __shared__ float pt_lds[64];
  __shared__ float crp[2];
  __shared__ float vvL[Hd];
  __shared__ float red[2][Hd];
  __shared__ float denr[2];

  int blk = blockIdx.x;               // == global row index
  int s = blk / NPSd;
  int irow = blk - s*NPSd;            // in-scene row
  size_t grow = (size_t)blk;

  int tid = threadIdx.x;              // 0..127
  int wave = tid >> 6, lane = tid & 63;

  // ---- mask (identical in both waves)
  int ml = lane < NPSd ? lane : NPSd-1;
  int mv = ts_mask[s*NPSd + ml];
  unsigned long long mb = __ballot(mv == 1 && lane < NPSd);
  float ne = (float)__popcll(mb);
  float scale = ne * 0.125f;          // ne / sqrt(A=64)
  bool rowv = (mb >> (unsigned)irow) & 1ULL;

  // ---- stage t (1 KB): thread owns h-pair
  int h2 = tid << 1;
  {
    float2 tv = *(const float2*)(temporal + grow*Hd + h2);
    t_lds[h2 >> 6][h2 & 63]       = tv.x;
    t_lds[h2 >> 6][(h2 & 63) + 1] = tv.y;
  }
  __syncthreads();

  // ---- phase 1: pt[a] = W2[a].t + b2[a]; wave w covers a = w*32..w*32+31
  int q = lane >> 4;                  // h-quarter owned by this lane
  float crw = 0.f;
#pragma unroll
  for (int p2 = 0; p2 < 2; ++p2) {
    int al = (wave*2 + p2)*16 + (lane & 15);
    const float4* w2p = (const float4*)(W2_w + (size_t)al*Hd + q*64);
    float p = 0.f;
#pragma unroll
    for (int m = 0; m < 16; ++m) {
      float4 wv = w2p[m];
      p += wv.x * t_lds[q][m*4+0];
      p += wv.y * t_lds[q][m*4+1];
      p += wv.z * t_lds[q][m*4+2];
      p += wv.w * t_lds[q][m*4+3];
    }
    p += __shfl_xor(p, 16);           // combine quarter pairs
    p += __shfl_xor(p, 32);           // combine halves -> full dot, all lanes
    float pfull = p + W2_b[al];
    float cb = pfull * W1_b[al];      // cr contribution
    cb += __shfl_xor(cb, 1);
    cb += __shfl_xor(cb, 2);
    cb += __shfl_xor(cb, 4);
    cb += __shfl_xor(cb, 8);          // sum over the 16 a's of this pass
    crw += cb;
    if (lane < 16) pt_lds[(wave*2 + p2)*16 + lane] = pfull;
  }
  if (lane == 0) crp[wave] = crw;
  barrier_lds();

  // ---- phase 2: v[h] = sum_a pt[a]*W1[a][h]; thread owns h-pair (coalesced)
  float2 v2 = make_float2(0.f, 0.f);
#pragma unroll 8
  for (int a = 0; a < 64; ++a) {
    float2 wv = *(const float2*)(W1_w + (size_t)a*Hd + h2);
    float pa = pt_lds[a];             // LDS broadcast
    v2.x += pa * wv.x;
    v2.y += pa * wv.y;
  }
  *(float2*)&vvL[h2] = v2;

  // ---- phase 3: wave w owns j = w*24 .. w*24+23; 6 chunks of 4, 2-deep
  const float* rb = spatial + grow*NPSd*Hd;
  int jb = wave*24;
  float4 A[4], B[4];

#define ISSUE(DST, C)                                                       \
  { _Pragma("unroll")                                                       \
    for (int rr = 0; rr < 4; ++rr)                                          \
      DST[rr] = *(const float4*)(rb + (size_t)(jb + (C)*4 + rr)*Hd          \
                                    + (lane << 2));                         \
    __builtin_amdgcn_sched_barrier(0); }

  ISSUE(A, 0);                        // in flight across the barrier
  barrier_lds();                      // vvL/crp ready (no vmcnt drain)

  float4 vv = *(const float4*)&vvL[lane << 2];
  float cr = crp[0] + crp[1];
  float4 o4 = make_float4(0.f, 0.f, 0.f, 0.f);
  float den = 0.f;

#define DO_CHUNK(CUR, C)                                                    \
  { _Pragma("unroll")                                                       \
    for (int rr = 0; rr < 4; ++rr) {                                        \
      int j = jb + (C)*4 + rr;                                              \
      float4 a4 = CUR[rr];                                                  \
      float pp = a4.x*vv.x + a4.y*vv.y + a4.z*vv.z + a4.w*vv.w;             \
      pp += __shfl_xor(pp, 1);                                              \
      pp += __shfl_xor(pp, 2);                                              \
      pp += __shfl_xor(pp, 4);                                              \
      pp += __shfl_xor(pp, 8);                                              \
      pp += __shfl_xor(pp, 16);                                             \
      pp += __shfl_xor(pp, 32);                                             \
      bool valid = rowv && ((mb >> (unsigned)j) & 1ULL) && (j != irow);     \
      float nj = valid ? __expf((pp + cr) * scale) : 0.f;                   \
      den += nj;                                                            \
      o4.x += nj*a4.x; o4.y += nj*a4.y; o4.z += nj*a4.z; o4.w += nj*a4.w;   \
    } }

  ISSUE(B, 1); DO_CHUNK(A, 0);
  ISSUE(A, 2); DO_CHUNK(B, 1);
  ISSUE(B, 3); DO_CHUNK(A, 2);
  ISSUE(A, 4); DO_CHUNK(B, 3);
  ISSUE(B, 5); DO_CHUNK(A, 4);
  DO_CHUNK(B, 5);

#undef ISSUE
#undef DO_CHUNK

  // ---- tail: 2-way cross-wave combine
  *(float4*)&red[wave][lane << 2] = o4;
  if (lane == 0) denr[wave] = den;
  barrier_lds();

  float dtot = denr[0] + denr[1];
  float inv = dtot > 0.f ? 1.f/dtot : 0.f;
  float2 oo;
  oo.x = (red[0][h2]     + red[1][h2])     * inv;
  oo.y = (red[0][h2 + 1] + red[1][h2 + 1]) * inv;
  *(float2*)(out + grow*Hd + h2) = oo;
}

// ---------------------------------------------------------------------------
extern "C" void kernel_launch(void* const* d_in, const int* in_sizes, int n_in,
                              void* d_out, int out_size, void* d_ws, size_t ws_size,
                              hipStream_t stream) {
  const float* spatial  = (const float*)d_in[0];
  const float* temporal = (const float*)d_in[1];
  const float* W1_w     = (const float*)d_in[2];
  const float* W1_b     = (const float*)d_in[3];
  const float* W2_w     = (const float*)d_in[4];
  const float* W2_b     = (const float*)d_in[5];
  const int*   ts_mask  = (const int*)d_in[6];
  float* out = (float*)d_out;

  fused_kernel<<<Nd, 128, 0, stream>>>(spatial, temporal, W1_w, W1_b,
                                       W2_w, W2_b, ts_mask, out);
}

// Round 10
// 52.738 us; speedup vs baseline: 2.0536x; 2.0536x over previous
//
#include <hip/hip_runtime.h>

#define Hd 256
#define NPSd 48
#define Sd 64
#define Nd (Sd*NPSd)

// LDS-only barrier: no vmcnt drain, in-flight global loads survive it.
__device__ __forceinline__ void barrier_lds() {
  asm volatile("s_waitcnt lgkmcnt(0)" ::: "memory");
  __builtin_amdgcn_s_barrier();
}

// ---------------------------------------------------------------------------
// One block = ONE agent row (grid 3072, 128 threads = 2 waves).
//  phase 1: pt = W2*t+b2  (waves split a-range)
//  phase 2: v = W1^T*pt   (thread owns h-pair, coalesced W1, pt broadcast)
//  phase 3: wave w scores+aggregates j = w*24..w*24+23 in 6 chunks of 4,
//           A/B 2-deep register pipeline, zero barriers.
//           Chunk reduce is TRANSPOSED: all 4 rows reduced together
//           (2x sel+xor32, 1x sel+xor16 -> each 16-lane group owns one row,
//           then xor 1/2/4/8, then 3 shuffles broadcast the njs back).
//  tail:    2-way cross-wave combine, one LDS barrier, write row.
// NOTE: no min-waves clause in launch_bounds -- R8's (128,6) capped VGPR at
// ~85 and spilled the A/B arrays to scratch (WRITE_SIZE 123 MB signature).
__global__ __launch_bounds__(128) void fused_kernel(
    const float* __restrict__ spatial,
    const float* __restrict__ temporal,
    const float* __restrict__ W1_w, const float* __restrict__ W1_b,
    const float* __restrict__ W2_w, const float* __restrict__ W2_b,
    const int* __restrict__ ts_mask,
    float* __restrict__ out) {
  __shared__ float t_lds[4][68];   // t in h-quarters, padded (bank spread)
  __shared__ float pt_lds[64];
  __shared__ float crp[2];
  __shared__ float vvL[Hd];
  __shared__ float red[2][Hd];
  __shared__ float denr[2];

  int blk = blockIdx.x;               // == global row index
  int s = blk / NPSd;
  int irow = blk - s*NPSd;            // in-scene row
  size_t grow = (size_t)blk;

  int tid = threadIdx.x;              // 0..127
  int wave = tid >> 6, lane = tid & 63;
  bool bit16 = (lane & 16) != 0;
  bool bit32 = (lane & 32) != 0;
  int g = (bit16 ? 1 : 0) | (bit32 ? 2 : 0);   // 16-lane group id

  // ---- mask (identical in both waves)
  int ml = lane < NPSd ? lane : NPSd-1;
  int mv = ts_mask[s*NPSd + ml];
  unsigned long long mb = __ballot(mv == 1 && lane < NPSd);
  float ne = (float)__popcll(mb);
  float scale = ne * 0.125f;          // ne / sqrt(A=64)
  bool rowv = (mb >> (unsigned)irow) & 1ULL;

  // ---- stage t (1 KB): thread owns h-pair
  int h2 = tid << 1;
  {
    float2 tv = *(const float2*)(temporal + grow*Hd + h2);
    t_lds[h2 >> 6][h2 & 63]       = tv.x;
    t_lds[h2 >> 6][(h2 & 63) + 1] = tv.y;
  }
  __syncthreads();

  // ---- phase 1: pt[a] = W2[a].t + b2[a]; wave w covers a = w*32..w*32+31
  int q = lane >> 4;                  // h-quarter owned by this lane
  float crw = 0.f;
#pragma unroll
  for (int p2 = 0; p2 < 2; ++p2) {
    int al = (wave*2 + p2)*16 + (lane & 15);
    const float4* w2p = (const float4*)(W2_w + (size_t)al*Hd + q*64);
    float p = 0.f;
#pragma unroll
    for (int m = 0; m < 16; ++m) {
      float4 wv = w2p[m];
      p += wv.x * t_lds[q][m*4+0];
      p += wv.y * t_lds[q][m*4+1];
      p += wv.z * t_lds[q][m*4+2];
      p += wv.w * t_lds[q][m*4+3];
    }
    p += __shfl_xor(p, 16);           // combine quarter pairs
    p += __shfl_xor(p, 32);           // combine halves -> full dot, all lanes
    float pfull = p + W2_b[al];
    float cb = pfull * W1_b[al];      // cr contribution
    cb += __shfl_xor(cb, 1);
    cb += __shfl_xor(cb, 2);
    cb += __shfl_xor(cb, 4);
    cb += __shfl_xor(cb, 8);          // sum over the 16 a's of this pass
    crw += cb;
    if (lane < 16) pt_lds[(wave*2 + p2)*16 + lane] = pfull;
  }
  if (lane == 0) crp[wave] = crw;
  barrier_lds();

  // ---- phase 2: v[h] = sum_a pt[a]*W1[a][h]; thread owns h-pair (coalesced)
  float2 v2 = make_float2(0.f, 0.f);
#pragma unroll 8
  for (int a = 0; a < 64; ++a) {
    float2 wv = *(const float2*)(W1_w + (size_t)a*Hd + h2);
    float pa = pt_lds[a];             // LDS broadcast
    v2.x += pa * wv.x;
    v2.y += pa * wv.y;
  }
  *(float2*)&vvL[h2] = v2;

  // ---- phase 3: wave w owns j = w*24 .. w*24+23; 6 chunks of 4, 2-deep
  const float* rb = spatial + grow*NPSd*Hd;
  int jb = wave*24;
  float4 A[4], B[4];

#define ISSUE(DST, C)                                                       \
  { _Pragma("unroll")                                                       \
    for (int rr = 0; rr < 4; ++rr)                                          \
      DST[rr] = *(const float4*)(rb + (size_t)(jb + (C)*4 + rr)*Hd          \
                                    + (lane << 2));                         \
    __builtin_amdgcn_sched_barrier(0); }

  ISSUE(A, 0);                        // in flight across the barrier
  barrier_lds();                      // vvL/crp ready (no vmcnt drain)

  float4 vv = *(const float4*)&vvL[lane << 2];
  float cr = crp[0] + crp[1];
  float4 o4 = make_float4(0.f, 0.f, 0.f, 0.f);
  float den = 0.f;

  // transposed 4-row reduce; each 16-lane group g ends owning row (C*4+g)
#define DO_CHUNK(CUR, C)                                                    \
  { float p0 = CUR[0].x*vv.x + CUR[0].y*vv.y + CUR[0].z*vv.z + CUR[0].w*vv.w;\
    float p1 = CUR[1].x*vv.x + CUR[1].y*vv.y + CUR[1].z*vv.z + CUR[1].w*vv.w;\
    float p2 = CUR[2].x*vv.x + CUR[2].y*vv.y + CUR[2].z*vv.z + CUR[2].w*vv.w;\
    float p3 = CUR[3].x*vv.x + CUR[3].y*vv.y + CUR[3].z*vv.z + CUR[3].w*vv.w;\
    float s0 = (bit32 ? p2 : p0) + __shfl_xor((bit32 ? p0 : p2), 32);       \
    float s1 = (bit32 ? p3 : p1) + __shfl_xor((bit32 ? p1 : p3), 32);       \
    float t  = (bit16 ? s1 : s0) + __shfl_xor((bit16 ? s0 : s1), 16);       \
    t += __shfl_xor(t, 1);                                                  \
    t += __shfl_xor(t, 2);                                                  \
    t += __shfl_xor(t, 4);                                                  \
    t += __shfl_xor(t, 8);                                                  \
    int jg = jb + (C)*4 + g;                                                \
    bool vg = rowv && ((mb >> (unsigned)jg) & 1ULL) && (jg != irow);        \
    float nj = vg ? __expf((t + cr) * scale) : 0.f;                         \
    float nB = __shfl_xor(nj, 16);                                          \
    float nC = __shfl_xor(nj, 32);                                          \
    float nD = __shfl_xor(nB, 32);                                          \
    _Pragma("unroll")                                                       \
    for (int rr = 0; rr < 4; ++rr) {                                        \
      int x = rr ^ g;                                                       \
      float n = (x == 0) ? nj : (x == 1) ? nB : (x == 2) ? nC : nD;         \
      den += n;                                                             \
      o4.x += n*CUR[rr].x; o4.y += n*CUR[rr].y;                             \
      o4.z += n*CUR[rr].z; o4.w += n*CUR[rr].w;                             \
    } }

  ISSUE(B, 1); DO_CHUNK(A, 0);
  ISSUE(A, 2); DO_CHUNK(B, 1);
  ISSUE(B, 3); DO_CHUNK(A, 2);
  ISSUE(A, 4); DO_CHUNK(B, 3);
  ISSUE(B, 5); DO_CHUNK(A, 4);
  DO_CHUNK(B, 5);

#undef ISSUE
#undef DO_CHUNK

  // ---- tail: 2-way cross-wave combine
  *(float4*)&red[wave][lane << 2] = o4;
  if (lane == 0) denr[wave] = den;
  barrier_lds();

  float dtot = denr[0] + denr[1];
  float inv = dtot > 0.f ? 1.f/dtot : 0.f;
  float2 oo;
  oo.x = (red[0][h2]     + red[1][h2])     * inv;
  oo.y = (red[0][h2 + 1] + red[1][h2 + 1]) * inv;
  *(float2*)(out + grow*Hd + h2) = oo;
}

// ---------------------------------------------------------------------------
extern "C" void kernel_launch(void* const* d_in, const int* in_sizes, int n_in,
                              void* d_out, int out_size, void* d_ws, size_t ws_size,
                              hipStream_t stream) {
  const float* spatial  = (const float*)d_in[0];
  const float* temporal = (const float*)d_in[1];
  const float* W1_w     = (const float*)d_in[2];
  const float* W1_b     = (const float*)d_in[3];
  const float* W2_w     = (const float*)d_in[4];
  const float* W2_b     = (const float*)d_in[5];
  const int*   ts_mask  = (const int*)d_in[6];
  float* out = (float*)d_out;

  fused_kernel<<<Nd, 128, 0, stream>>>(spatial, temporal, W1_w, W1_b,
                                       W2_w, W2_b, ts_mask, out);
}

// Round 11
// 43.615 us; speedup vs baseline: 2.4831x; 1.2092x over previous
//
#include <hip/hip_runtime.h>

#define Hd 256
#define NPSd 48
#define Sd 64
#define Nd (Sd*NPSd)
#define ROWS 4   // rows per prep block

// LDS-only barrier: no vmcnt drain, in-flight global loads survive it.
__device__ __forceinline__ void barrier_lds() {
  asm volatile("s_waitcnt lgkmcnt(0)" ::: "memory");
  __builtin_amdgcn_s_barrier();
}

// ---------------------------------------------------------------------------
// Prep kernel (R7 phases 1-2, proven): per 4 rows compute
//   pt = W2*t+b2, v = W1^T*pt, cr = b1.pt   -> v_ws[row][256], c_ws[row]
__global__ __launch_bounds__(256) void prep_kernel(
    const float* __restrict__ temporal,
    const float* __restrict__ W1_w, const float* __restrict__ W1_b,
    const float* __restrict__ W2_w, const float* __restrict__ W2_b,
    float* __restrict__ v_ws, float* __restrict__ c_ws) {
  __shared__ float t_lds[ROWS][4][72];
  __shared__ float pt_lds[ROWS][64];
  __shared__ float crp[4][ROWS];
  __shared__ float vred[ROWS][4][Hd];

  int row0 = blockIdx.x * ROWS;
  int tid = threadIdx.x;
  int wave = tid >> 6, lane = tid & 63;

  int al = (wave<<4) + (lane & 15);
  int q  = lane >> 4;
  float b1v = W1_b[al];
  float b2v = W2_b[al];

  {
    int r = tid >> 6, h4 = (tid & 63) << 2;
    float4 tv = *(const float4*)(temporal + (size_t)(row0 + r)*Hd + h4);
    *(float4*)&t_lds[r][h4 >> 6][h4 & 63] = tv;
  }

  float4 w2r[16];
#pragma unroll
  for (int m = 0; m < 16; ++m)
    w2r[m] = *(const float4*)(W2_w + (size_t)al*Hd + q*64 + m*4);

  __syncthreads();

#pragma unroll
  for (int r = 0; r < ROWS; ++r) {
    float p = 0.f;
#pragma unroll
    for (int m = 0; m < 16; ++m) {
      float4 wv = w2r[m];
      p += wv.x * t_lds[r][q][m*4+0];
      p += wv.y * t_lds[r][q][m*4+1];
      p += wv.z * t_lds[r][q][m*4+2];
      p += wv.w * t_lds[r][q][m*4+3];
    }
    p += __shfl_xor(p, 16);
    p += __shfl_xor(p, 32);
    float pfull = p + b2v;
    float cb = pfull * b1v;
    cb += __shfl_xor(cb, 1);
    cb += __shfl_xor(cb, 2);
    cb += __shfl_xor(cb, 4);
    cb += __shfl_xor(cb, 8);
    if (lane < 16) pt_lds[r][(wave<<4) + lane] = pfull;
    if (lane == 0) crp[wave][r] = cb;
  }
  barrier_lds();

  float4 w1r[16];
#pragma unroll
  for (int j = 0; j < 16; ++j)
    w1r[j] = *(const float4*)(W1_w + (size_t)((wave<<4)+j)*Hd + (lane<<2));

#pragma unroll
  for (int r = 0; r < ROWS; ++r) {
    float4 v4 = make_float4(0.f,0.f,0.f,0.f);
#pragma unroll
    for (int j = 0; j < 16; ++j) {
      float pj = pt_lds[r][(wave<<4)+j];
      float4 wv = w1r[j];
      v4.x += pj*wv.x; v4.y += pj*wv.y; v4.z += pj*wv.z; v4.w += pj*wv.w;
    }
    *(float4*)&vred[r][wave][lane<<2] = v4;
  }
  barrier_lds();

#pragma unroll
  for (int r = 0; r < ROWS; ++r) {
    float vv = vred[r][0][tid] + vred[r][1][tid]
             + vred[r][2][tid] + vred[r][3][tid];
    v_ws[(size_t)(row0 + r)*Hd + tid] = vv;
  }
  if (tid < ROWS)
    c_ws[row0 + tid] = crp[0][tid] + crp[1][tid] + crp[2][tid] + crp[3][tid];
}

// ---------------------------------------------------------------------------
// Streaming kernel: NO weights. Block = 2 rows x 2 waves/row (grid 1536,
// 24 waves/CU). Wave handles 24 j's of its row: 6 chunks of 4, 3-deep
// A/B/C register pipeline (12 KB/wave in flight), zero barriers until one
// final 2-way LDS combine. Serial per-j butterfly (R7's proven reduce).
__global__ __launch_bounds__(256) void stream_kernel(
    const float* __restrict__ spatial,
    const float* __restrict__ v_ws, const float* __restrict__ c_ws,
    const int* __restrict__ ts_mask,
    float* __restrict__ out) {
  __shared__ float red[4][Hd];
  __shared__ float denr[4];

  int blk = blockIdx.x;
  int tid = threadIdx.x;
  int wave = tid >> 6, lane = tid & 63;
  int rloc = wave >> 1;               // 0,1: row within block
  int half = wave & 1;                // 0,1: j-half within row

  int row  = blk*2 + rloc;            // global row
  int s    = row / NPSd;
  int irow = row - s*NPSd;

  // mask (scene-wide; both rows of the block are in the same scene)
  int ml = lane < NPSd ? lane : NPSd-1;
  int mv = ts_mask[s*NPSd + ml];
  unsigned long long mb = __ballot(mv == 1 && lane < NPSd);
  float ne = (float)__popcll(mb);
  float scale = ne * 0.125f;          // ne / sqrt(A=64)
  bool rowv = (mb >> (unsigned)irow) & 1ULL;

  // per-row v, cr (tiny L2 loads, issued before the spatial stream)
  float4 vv = *(const float4*)(v_ws + (size_t)row*Hd + (lane<<2));
  float cr = c_ws[row];

  const float* rb = spatial + (size_t)row*NPSd*Hd;
  int jb = half*24;
  float4 A[4], B[4], C[4];

#define ISSUE(DST, Ch)                                                      \
  { _Pragma("unroll")                                                       \
    for (int rr = 0; rr < 4; ++rr)                                          \
      DST[rr] = *(const float4*)(rb + (size_t)(jb + (Ch)*4 + rr)*Hd         \
                                    + (lane << 2));                         \
    __builtin_amdgcn_sched_barrier(0); }

  float4 o4 = make_float4(0.f, 0.f, 0.f, 0.f);
  float den = 0.f;

#define DO_CHUNK(CUR, Ch)                                                   \
  { _Pragma("unroll")                                                       \
    for (int rr = 0; rr < 4; ++rr) {                                        \
      int j = jb + (Ch)*4 + rr;                                             \
      float4 a4 = CUR[rr];                                                  \
      float pp = a4.x*vv.x + a4.y*vv.y + a4.z*vv.z + a4.w*vv.w;             \
      pp += __shfl_xor(pp, 1);                                              \
      pp += __shfl_xor(pp, 2);                                              \
      pp += __shfl_xor(pp, 4);                                              \
      pp += __shfl_xor(pp, 8);                                              \
      pp += __shfl_xor(pp, 16);                                             \
      pp += __shfl_xor(pp, 32);                                             \
      bool valid = rowv && ((mb >> (unsigned)j) & 1ULL) && (j != irow);     \
      float nj = valid ? __expf((pp + cr) * scale) : 0.f;                   \
      den += nj;                                                            \
      o4.x += nj*a4.x; o4.y += nj*a4.y; o4.z += nj*a4.z; o4.w += nj*a4.w;   \
    } }

  ISSUE(A, 0); ISSUE(B, 1); ISSUE(C, 2);
  DO_CHUNK(A, 0); ISSUE(A, 3);
  DO_CHUNK(B, 1); ISSUE(B, 4);
  DO_CHUNK(C, 2); ISSUE(C, 5);
  DO_CHUNK(A, 3);
  DO_CHUNK(B, 4);
  DO_CHUNK(C, 5);

#undef ISSUE
#undef DO_CHUNK

  // 2-way combine per row (one barrier for the whole kernel)
  *(float4*)&red[wave][lane << 2] = o4;
  if (lane == 0) denr[wave] = den;
  barrier_lds();

  {
    float d0 = denr[0] + denr[1];
    float i0v = d0 > 0.f ? 1.f/d0 : 0.f;
    out[(size_t)(blk*2)*Hd + tid] = (red[0][tid] + red[1][tid]) * i0v;
    float d1 = denr[2] + denr[3];
    float i1v = d1 > 0.f ? 1.f/d1 : 0.f;
    out[(size_t)(blk*2 + 1)*Hd + tid] = (red[2][tid] + red[3][tid]) * i1v;
  }
}

// ---------------------------------------------------------------------------
extern "C" void kernel_launch(void* const* d_in, const int* in_sizes, int n_in,
                              void* d_out, int out_size, void* d_ws, size_t ws_size,
                              hipStream_t stream) {
  const float* spatial  = (const float*)d_in[0];
  const float* temporal = (const float*)d_in[1];
  const float* W1_w     = (const float*)d_in[2];
  const float* W1_b     = (const float*)d_in[3];
  const float* W2_w     = (const float*)d_in[4];
  const float* W2_b     = (const float*)d_in[5];
  const int*   ts_mask  = (const int*)d_in[6];
  float* out = (float*)d_out;

  float* ws = (float*)d_ws;
  float* v_ws = ws;                    // N*H floats
  float* c_ws = v_ws + (size_t)Nd*Hd;  // N floats

  prep_kernel<<<Nd/ROWS, 256, 0, stream>>>(temporal, W1_w, W1_b, W2_w, W2_b,
                                           v_ws, c_ws);
  stream_kernel<<<Nd/2, 256, 0, stream>>>(spatial, v_ws, c_ws, ts_mask, out);
}

// Round 12
// 27.788 us; speedup vs baseline: 3.8973x; 1.5695x over previous
//
#include <hip/hip_runtime.h>

#define Hd 256
#define NPSd 48
#define Sd 64
#define Nd (Sd*NPSd)
#define ROWS 4   // rows per prep block

// LDS-only barrier: no vmcnt drain, in-flight global loads survive it.
__device__ __forceinline__ void barrier_lds() {
  asm volatile("s_waitcnt lgkmcnt(0)" ::: "memory");
  __builtin_amdgcn_s_barrier();
}

// ---------------------------------------------------------------------------
// Prep kernel (unchanged from R10): per 4 rows compute
//   pt = W2*t+b2, v = W1^T*pt, cr = b1.pt   -> v_ws[row][256], c_ws[row]
__global__ __launch_bounds__(256) void prep_kernel(
    const float* __restrict__ temporal,
    const float* __restrict__ W1_w, const float* __restrict__ W1_b,
    const float* __restrict__ W2_w, const float* __restrict__ W2_b,
    float* __restrict__ v_ws, float* __restrict__ c_ws) {
  __shared__ float t_lds[ROWS][4][72];
  __shared__ float pt_lds[ROWS][64];
  __shared__ float crp[4][ROWS];
  __shared__ float vred[ROWS][4][Hd];

  int row0 = blockIdx.x * ROWS;
  int tid = threadIdx.x;
  int wave = tid >> 6, lane = tid & 63;

  int al = (wave<<4) + (lane & 15);
  int q  = lane >> 4;
  float b1v = W1_b[al];
  float b2v = W2_b[al];

  {
    int r = tid >> 6, h4 = (tid & 63) << 2;
    float4 tv = *(const float4*)(temporal + (size_t)(row0 + r)*Hd + h4);
    *(float4*)&t_lds[r][h4 >> 6][h4 & 63] = tv;
  }

  float4 w2r[16];
#pragma unroll
  for (int m = 0; m < 16; ++m)
    w2r[m] = *(const float4*)(W2_w + (size_t)al*Hd + q*64 + m*4);

  __syncthreads();

#pragma unroll
  for (int r = 0; r < ROWS; ++r) {
    float p = 0.f;
#pragma unroll
    for (int m = 0; m < 16; ++m) {
      float4 wv = w2r[m];
      p += wv.x * t_lds[r][q][m*4+0];
      p += wv.y * t_lds[r][q][m*4+1];
      p += wv.z * t_lds[r][q][m*4+2];
      p += wv.w * t_lds[r][q][m*4+3];
    }
    p += __shfl_xor(p, 16);
    p += __shfl_xor(p, 32);
    float pfull = p + b2v;
    float cb = pfull * b1v;
    cb += __shfl_xor(cb, 1);
    cb += __shfl_xor(cb, 2);
    cb += __shfl_xor(cb, 4);
    cb += __shfl_xor(cb, 8);
    if (lane < 16) pt_lds[r][(wave<<4) + lane] = pfull;
    if (lane == 0) crp[wave][r] = cb;
  }
  barrier_lds();

  float4 w1r[16];
#pragma unroll
  for (int j = 0; j < 16; ++j)
    w1r[j] = *(const float4*)(W1_w + (size_t)((wave<<4)+j)*Hd + (lane<<2));

#pragma unroll
  for (int r = 0; r < ROWS; ++r) {
    float4 v4 = make_float4(0.f,0.f,0.f,0.f);
#pragma unroll
    for (int j = 0; j < 16; ++j) {
      float pj = pt_lds[r][(wave<<4)+j];
      float4 wv = w1r[j];
      v4.x += pj*wv.x; v4.y += pj*wv.y; v4.z += pj*wv.z; v4.w += pj*wv.w;
    }
    *(float4*)&vred[r][wave][lane<<2] = v4;
  }
  barrier_lds();

#pragma unroll
  for (int r = 0; r < ROWS; ++r) {
    float vv = vred[r][0][tid] + vred[r][1][tid]
             + vred[r][2][tid] + vred[r][3][tid];
    v_ws[(size_t)(row0 + r)*Hd + tid] = vv;
  }
  if (tid < ROWS)
    c_ws[row0 + tid] = crp[0][tid] + crp[1][tid] + crp[2][tid] + crp[3][tid];
}

// ---------------------------------------------------------------------------
// Streaming kernel with MASK-COMPACTED column list: only rows j with
// mask[j]==1 are ever loaded; rows i with mask[i]==0 load nothing.
// Block = 2 rows x 2 waves/row (grid 1536). Wave streams its contiguous
// slot range of the compact list in 4-row chunks, A/B 2-deep register
// pipeline (static reg names, runtime chunk index), zero barriers in the
// loop; one 2-way LDS combine at the end.
__global__ __launch_bounds__(256) void stream_kernel(
    const float* __restrict__ spatial,
    const float* __restrict__ v_ws, const float* __restrict__ c_ws,
    const int* __restrict__ ts_mask,
    float* __restrict__ out) {
  __shared__ float red[4][Hd];
  __shared__ float denr[4];
  __shared__ int   jl[NPSd];

  int blk = blockIdx.x;
  int tid = threadIdx.x;
  int wave = tid >> 6, lane = tid & 63;
  int rloc = wave >> 1;               // 0,1: row within block
  int half = wave & 1;                // 0,1: slot-half within row

  int row  = blk*2 + rloc;            // global row (both rows same scene)
  int s    = row / NPSd;
  int irow = row - s*NPSd;

  // mask (scene-wide)
  int ml = lane < NPSd ? lane : NPSd-1;
  int mv = ts_mask[s*NPSd + ml];
  unsigned long long mb = __ballot(mv == 1 && lane < NPSd);
  int   nv = __popcll(mb);            // number of existing agents
  float ne = (float)nv;
  float scale = ne * 0.125f;          // ne / sqrt(A=64)
  bool rowv = (mb >> (unsigned)irow) & 1ULL;

  // per-row v, cr (tiny L2 loads, in flight across list build)
  float4 vv = *(const float4*)(v_ws + (size_t)row*Hd + (lane<<2));
  float cr = c_ws[row];

  // build compact valid-j list (wave 0 writes; identical in all waves)
  if (wave == 0 && lane < NPSd) {
    bool val = (mb >> (unsigned)lane) & 1ULL;
    int pos = __popcll(mb & ((1ULL << (unsigned)lane) - 1ULL));
    if (val) jl[pos] = lane;
  }
  barrier_lds();

  const float* rb = spatial + (size_t)row*NPSd*Hd;
  float4 o4 = make_float4(0.f, 0.f, 0.f, 0.f);
  float den = 0.f;

  // this wave's slot range [start, end)
  int mid = (nv + 1) >> 1;
  int start = half ? mid : 0;
  int end   = half ? nv  : mid;
  int nl    = end - start;

  if (rowv && nl > 0) {
    int nc = (nl + 3) >> 2;           // chunks of 4
    float4 A[4], B[4];
    int jA[4], jB[4];

#define ISSUE(DST, JD, C)                                                   \
    { _Pragma("unroll")                                                     \
      for (int rr = 0; rr < 4; ++rr) {                                      \
        int slot = start + (C)*4 + rr;                                      \
        int si = slot < end ? slot : end - 1;                               \
        int j = jl[si];                                                     \
        JD[rr] = (slot < end) ? j : -1;                                     \
        DST[rr] = *(const float4*)(rb + (size_t)j*Hd + (lane << 2));        \
      }                                                                     \
      __builtin_amdgcn_sched_barrier(0); }

#define DO_CHUNK(CUR, JC)                                                   \
    { _Pragma("unroll")                                                     \
      for (int rr = 0; rr < 4; ++rr) {                                      \
        int j = JC[rr];                                                     \
        float4 a4 = CUR[rr];                                                \
        float pp = a4.x*vv.x + a4.y*vv.y + a4.z*vv.z + a4.w*vv.w;           \
        pp += __shfl_xor(pp, 1);                                            \
        pp += __shfl_xor(pp, 2);                                            \
        pp += __shfl_xor(pp, 4);                                            \
        pp += __shfl_xor(pp, 8);                                            \
        pp += __shfl_xor(pp, 16);                                           \
        pp += __shfl_xor(pp, 32);                                           \
        bool valid = (j >= 0) && (j != irow);                               \
        float nj = valid ? __expf((pp + cr) * scale) : 0.f;                 \
        den += nj;                                                          \
        o4.x += nj*a4.x; o4.y += nj*a4.y; o4.z += nj*a4.z; o4.w += nj*a4.w; \
      } }

    ISSUE(A, jA, 0);
    if (nc > 1) ISSUE(B, jB, 1);
    int c = 0;
    while (true) {
      DO_CHUNK(A, jA);
      if (c + 2 < nc) ISSUE(A, jA, c + 2);
      ++c; if (c >= nc) break;
      DO_CHUNK(B, jB);
      if (c + 2 < nc) ISSUE(B, jB, c + 2);
      ++c; if (c >= nc) break;
    }
#undef ISSUE
#undef DO_CHUNK
  }

  // 2-way combine per row (one barrier)
  *(float4*)&red[wave][lane << 2] = o4;
  if (lane == 0) denr[wave] = den;
  barrier_lds();

  {
    float d0 = denr[0] + denr[1];
    float i0v = d0 > 0.f ? 1.f/d0 : 0.f;
    out[(size_t)(blk*2)*Hd + tid] = (red[0][tid] + red[1][tid]) * i0v;
    float d1 = denr[2] + denr[3];
    float i1v = d1 > 0.f ? 1.f/d1 : 0.f;
    out[(size_t)(blk*2 + 1)*Hd + tid] = (red[2][tid] + red[3][tid]) * i1v;
  }
}

// ---------------------------------------------------------------------------
extern "C" void kernel_launch(void* const* d_in, const int* in_sizes, int n_in,
                              void* d_out, int out_size, void* d_ws, size_t ws_size,
                              hipStream_t stream) {
  const float* spatial  = (const float*)d_in[0];
  const float* temporal = (const float*)d_in[1];
  const float* W1_w     = (const float*)d_in[2];
  const float* W1_b     = (const float*)d_in[3];
  const float* W2_w     = (const float*)d_in[4];
  const float* W2_b     = (const float*)d_in[5];
  const int*   ts_mask  = (const int*)d_in[6];
  float* out = (float*)d_out;

  float* ws = (float*)d_ws;
  float* v_ws = ws;                    // N*H floats
  float* c_ws = v_ws + (size_t)Nd*Hd;  // N floats

  prep_kernel<<<Nd/ROWS, 256, 0, stream>>>(temporal, W1_w, W1_b, W2_w, W2_b,
                                           v_ws, c_ws);
  stream_kernel<<<Nd/2, 256, 0, stream>>>(spatial, v_ws, c_ws, ts_mask, out);
}

// Round 13
// 27.536 us; speedup vs baseline: 3.9331x; 1.0092x over previous
//
#include <hip/hip_runtime.h>

#define Hd 256
#define NPSd 48
#define Sd 64
#define Nd (Sd*NPSd)
#define ROWS 4   // rows per prep block

// LDS-only barrier: no vmcnt drain, in-flight global loads survive it.
__device__ __forceinline__ void barrier_lds() {
  asm volatile("s_waitcnt lgkmcnt(0)" ::: "memory");
  __builtin_amdgcn_s_barrier();
}

// ---------------------------------------------------------------------------
// Prep kernel (unchanged, proven): per 4 rows compute
//   pt = W2*t+b2, v = W1^T*pt, cr = b1.pt   -> v_ws[row][256], c_ws[row]
__global__ __launch_bounds__(256) void prep_kernel(
    const float* __restrict__ temporal,
    const float* __restrict__ W1_w, const float* __restrict__ W1_b,
    const float* __restrict__ W2_w, const float* __restrict__ W2_b,
    float* __restrict__ v_ws, float* __restrict__ c_ws) {
  __shared__ float t_lds[ROWS][4][72];
  __shared__ float pt_lds[ROWS][64];
  __shared__ float crp[4][ROWS];
  __shared__ float vred[ROWS][4][Hd];

  int row0 = blockIdx.x * ROWS;
  int tid = threadIdx.x;
  int wave = tid >> 6, lane = tid & 63;

  int al = (wave<<4) + (lane & 15);
  int q  = lane >> 4;
  float b1v = W1_b[al];
  float b2v = W2_b[al];

  {
    int r = tid >> 6, h4 = (tid & 63) << 2;
    float4 tv = *(const float4*)(temporal + (size_t)(row0 + r)*Hd + h4);
    *(float4*)&t_lds[r][h4 >> 6][h4 & 63] = tv;
  }

  float4 w2r[16];
#pragma unroll
  for (int m = 0; m < 16; ++m)
    w2r[m] = *(const float4*)(W2_w + (size_t)al*Hd + q*64 + m*4);

  __syncthreads();

#pragma unroll
  for (int r = 0; r < ROWS; ++r) {
    float p = 0.f;
#pragma unroll
    for (int m = 0; m < 16; ++m) {
      float4 wv = w2r[m];
      p += wv.x * t_lds[r][q][m*4+0];
      p += wv.y * t_lds[r][q][m*4+1];
      p += wv.z * t_lds[r][q][m*4+2];
      p += wv.w * t_lds[r][q][m*4+3];
    }
    p += __shfl_xor(p, 16);
    p += __shfl_xor(p, 32);
    float pfull = p + b2v;
    float cb = pfull * b1v;
    cb += __shfl_xor(cb, 1);
    cb += __shfl_xor(cb, 2);
    cb += __shfl_xor(cb, 4);
    cb += __shfl_xor(cb, 8);
    if (lane < 16) pt_lds[r][(wave<<4) + lane] = pfull;
    if (lane == 0) crp[wave][r] = cb;
  }
  barrier_lds();

  float4 w1r[16];
#pragma unroll
  for (int j = 0; j < 16; ++j)
    w1r[j] = *(const float4*)(W1_w + (size_t)((wave<<4)+j)*Hd + (lane<<2));

#pragma unroll
  for (int r = 0; r < ROWS; ++r) {
    float4 v4 = make_float4(0.f,0.f,0.f,0.f);
#pragma unroll
    for (int j = 0; j < 16; ++j) {
      float pj = pt_lds[r][(wave<<4)+j];
      float4 wv = w1r[j];
      v4.x += pj*wv.x; v4.y += pj*wv.y; v4.z += pj*wv.z; v4.w += pj*wv.w;
    }
    *(float4*)&vred[r][wave][lane<<2] = v4;
  }
  barrier_lds();

#pragma unroll
  for (int r = 0; r < ROWS; ++r) {
    float vv = vred[r][0][tid] + vred[r][1][tid]
             + vred[r][2][tid] + vred[r][3][tid];
    v_ws[(size_t)(row0 + r)*Hd + tid] = vv;
  }
  if (tid < ROWS)
    c_ws[row0 + tid] = crp[0][tid] + crp[1][tid] + crp[2][tid] + crp[3][tid];
}

// ---------------------------------------------------------------------------
// Streaming kernel: ONE WAVE PER ROW (grid 3072 x 64 threads). Zero LDS,
// zero barriers. Compact valid-j list lives in registers: lane l holds the
// l-th set bit of the scene mask (binary search), chunk issue fetches j via
// __shfl. 3-deep 4-row register pipeline; invalid rows write zeros and exit.
__global__ __launch_bounds__(64) void stream_kernel(
    const float* __restrict__ spatial,
    const float* __restrict__ v_ws, const float* __restrict__ c_ws,
    const int* __restrict__ ts_mask,
    float* __restrict__ out) {
  int row  = blockIdx.x;              // global row
  int s    = row / NPSd;
  int irow = row - s*NPSd;
  int lane = threadIdx.x;             // 0..63

  // scene mask
  int ml = lane < NPSd ? lane : NPSd-1;
  int mv = ts_mask[s*NPSd + ml];
  unsigned long long mb = __ballot(mv == 1 && lane < NPSd);
  int nv = __popcll(mb);
  float scale = (float)nv * 0.125f;   // ne / sqrt(A=64)
  bool rowv = (mb >> (unsigned)irow) & 1ULL;

  // per-row v, cr (small L2 loads)
  float4 vv = *(const float4*)(v_ws + (size_t)row*Hd + (lane<<2));
  float cr = c_ws[row];

  float4 o4 = make_float4(0.f, 0.f, 0.f, 0.f);
  float den = 0.f;

  if (rowv && nv > 1) {
    // lane l finds the l-th set bit of mb (in-register compact list)
    unsigned long long m = mb;
    int k = lane, jbit = 0, pc;
    pc = __popcll(m & 0xFFFFFFFFull); if (k >= pc) { jbit += 32; k -= pc; m >>= 32; }
    pc = __popcll(m & 0xFFFFull);     if (k >= pc) { jbit += 16; k -= pc; m >>= 16; }
    pc = __popcll(m & 0xFFull);       if (k >= pc) { jbit += 8;  k -= pc; m >>= 8; }
    pc = __popcll(m & 0xFull);        if (k >= pc) { jbit += 4;  k -= pc; m >>= 4; }
    pc = __popcll(m & 0x3ull);        if (k >= pc) { jbit += 2;  k -= pc; m >>= 2; }
    pc = (int)(m & 1ull);             if (k >= pc) { jbit += 1; }

    const float* rb = spatial + (size_t)row*NPSd*Hd;
    int nc = (nv + 3) >> 2;           // chunks of 4 slots
    float4 A[4], B[4], C[4];
    int jA[4], jB[4], jC[4];

#define ISSUE(DST, JD, Ch)                                                  \
    { _Pragma("unroll")                                                     \
      for (int rr = 0; rr < 4; ++rr) {                                      \
        int slot = (Ch)*4 + rr;                                             \
        int ss = slot < nv ? slot : 0;                                      \
        int j = __shfl(jbit, ss);                                           \
        JD[rr] = slot < nv ? j : -1;                                        \
        DST[rr] = *(const float4*)(rb + (size_t)j*Hd + (lane << 2));        \
      }                                                                     \
      __builtin_amdgcn_sched_barrier(0); }

#define DO_CHUNK(CUR, JC2)                                                  \
    { _Pragma("unroll")                                                     \
      for (int rr = 0; rr < 4; ++rr) {                                      \
        int j = JC2[rr];                                                    \
        float4 a4 = CUR[rr];                                                \
        float pp = a4.x*vv.x + a4.y*vv.y + a4.z*vv.z + a4.w*vv.w;           \
        pp += __shfl_xor(pp, 1);                                            \
        pp += __shfl_xor(pp, 2);                                            \
        pp += __shfl_xor(pp, 4);                                            \
        pp += __shfl_xor(pp, 8);                                            \
        pp += __shfl_xor(pp, 16);                                           \
        pp += __shfl_xor(pp, 32);                                           \
        bool valid = (j >= 0) && (j != irow);                               \
        float nj = valid ? __expf((pp + cr) * scale) : 0.f;                 \
        den += nj;                                                          \
        o4.x += nj*a4.x; o4.y += nj*a4.y; o4.z += nj*a4.z; o4.w += nj*a4.w; \
      } }

    ISSUE(A, jA, 0);
    if (nc > 1) ISSUE(B, jB, 1);
    if (nc > 2) ISSUE(C, jC, 2);
    int cc = 0;
    while (true) {
      DO_CHUNK(A, jA); if (cc + 3 < nc) ISSUE(A, jA, cc + 3);
      ++cc; if (cc >= nc) break;
      DO_CHUNK(B, jB); if (cc + 3 < nc) ISSUE(B, jB, cc + 3);
      ++cc; if (cc >= nc) break;
      DO_CHUNK(C, jC); if (cc + 3 < nc) ISSUE(C, jC, cc + 3);
      ++cc; if (cc >= nc) break;
    }
#undef ISSUE
#undef DO_CHUNK
  }

  float inv = den > 0.f ? 1.f/den : 0.f;
  o4.x *= inv; o4.y *= inv; o4.z *= inv; o4.w *= inv;
  *(float4*)(out + (size_t)row*Hd + (lane<<2)) = o4;
}

// ---------------------------------------------------------------------------
extern "C" void kernel_launch(void* const* d_in, const int* in_sizes, int n_in,
                              void* d_out, int out_size, void* d_ws, size_t ws_size,
                              hipStream_t stream) {
  const float* spatial  = (const float*)d_in[0];
  const float* temporal = (const float*)d_in[1];
  const float* W1_w     = (const float*)d_in[2];
  const float* W1_b     = (const float*)d_in[3];
  const float* W2_w     = (const float*)d_in[4];
  const float* W2_b     = (const float*)d_in[5];
  const int*   ts_mask  = (const int*)d_in[6];
  float* out = (float*)d_out;

  float* ws = (float*)d_ws;
  float* v_ws = ws;                    // N*H floats
  float* c_ws = v_ws + (size_t)Nd*Hd;  // N floats

  prep_kernel<<<Nd/ROWS, 256, 0, stream>>>(temporal, W1_w, W1_b, W2_w, W2_b,
                                           v_ws, c_ws);
  stream_kernel<<<Nd, 64, 0, stream>>>(spatial, v_ws, c_ws, ts_mask, out);
}

// Round 14
// 23.989 us; speedup vs baseline: 4.5146x; 1.1479x over previous
//
#include <hip/hip_runtime.h>

#define Hd 256
#define NPSd 48
#define Sd 64
#define Nd (Sd*NPSd)
#define ROWS 4   // rows per block

// LDS-only barrier: no vmcnt drain, in-flight global loads survive it.
__device__ __forceinline__ void barrier_lds() {
  asm volatile("s_waitcnt lgkmcnt(0)" ::: "memory");
  __builtin_amdgcn_s_barrier();
}

// ---------------------------------------------------------------------------
// Fused kernel: 768 blocks x 256 thr; block = 4 consecutive rows of 1 scene.
// Phase A (prep, R10-proven): pt = W2*t+b2, v = W1^T*pt -> LDS, cr -> LDS.
// Phase B (stream, R12-proven): wave w streams row w's mask-compacted j-list
// with a 3-deep register pipeline; direct output write, no cross-wave work.
__global__ __launch_bounds__(256) void fused_kernel(
    const float* __restrict__ spatial,
    const float* __restrict__ temporal,
    const float* __restrict__ W1_w, const float* __restrict__ W1_b,
    const float* __restrict__ W2_w, const float* __restrict__ W2_b,
    const int* __restrict__ ts_mask,
    float* __restrict__ out) {
  __shared__ float t_lds[ROWS][4][72];
  __shared__ float pt_lds[ROWS][64];
  __shared__ float crp[4][ROWS];
  __shared__ float vred[ROWS][4][Hd];   // 16 KB
  __shared__ float vvL[ROWS][Hd];       // 4 KB
  __shared__ float crL[ROWS];

  int row0 = blockIdx.x * ROWS;
  int s    = row0 / NPSd;
  int i0   = row0 - s*NPSd;
  int tid  = threadIdx.x;
  int wave = tid >> 6, lane = tid & 63;

  // ---------------- Phase A: prep (verbatim R10 structure) ----------------
  int al = (wave<<4) + (lane & 15);
  int q  = lane >> 4;
  float b1v = W1_b[al];
  float b2v = W2_b[al];

  {
    int r = tid >> 6, h4 = (tid & 63) << 2;
    float4 tv = *(const float4*)(temporal + (size_t)(row0 + r)*Hd + h4);
    *(float4*)&t_lds[r][h4 >> 6][h4 & 63] = tv;
  }

  float4 w2r[16];
#pragma unroll
  for (int m = 0; m < 16; ++m)
    w2r[m] = *(const float4*)(W2_w + (size_t)al*Hd + q*64 + m*4);

  __syncthreads();

#pragma unroll
  for (int r = 0; r < ROWS; ++r) {
    float p = 0.f;
#pragma unroll
    for (int m = 0; m < 16; ++m) {
      float4 wv = w2r[m];
      p += wv.x * t_lds[r][q][m*4+0];
      p += wv.y * t_lds[r][q][m*4+1];
      p += wv.z * t_lds[r][q][m*4+2];
      p += wv.w * t_lds[r][q][m*4+3];
    }
    p += __shfl_xor(p, 16);
    p += __shfl_xor(p, 32);
    float pfull = p + b2v;
    float cb = pfull * b1v;
    cb += __shfl_xor(cb, 1);
    cb += __shfl_xor(cb, 2);
    cb += __shfl_xor(cb, 4);
    cb += __shfl_xor(cb, 8);
    if (lane < 16) pt_lds[r][(wave<<4) + lane] = pfull;
    if (lane == 0) crp[wave][r] = cb;
  }
  barrier_lds();

  float4 w1r[16];
#pragma unroll
  for (int j = 0; j < 16; ++j)
    w1r[j] = *(const float4*)(W1_w + (size_t)((wave<<4)+j)*Hd + (lane<<2));

#pragma unroll
  for (int r = 0; r < ROWS; ++r) {
    float4 v4 = make_float4(0.f,0.f,0.f,0.f);
#pragma unroll
    for (int j = 0; j < 16; ++j) {
      float pj = pt_lds[r][(wave<<4)+j];
      float4 wv = w1r[j];
      v4.x += pj*wv.x; v4.y += pj*wv.y; v4.z += pj*wv.z; v4.w += pj*wv.w;
    }
    *(float4*)&vred[r][wave][lane<<2] = v4;
  }
  barrier_lds();

#pragma unroll
  for (int r = 0; r < ROWS; ++r)
    vvL[r][tid] = vred[r][0][tid] + vred[r][1][tid]
                + vred[r][2][tid] + vred[r][3][tid];
  if (tid < ROWS)
    crL[tid] = crp[0][tid] + crp[1][tid] + crp[2][tid] + crp[3][tid];
  barrier_lds();

  // ---------------- Phase B: stream (verbatim R12 core) -------------------
  int row  = row0 + wave;             // this wave's row
  int irow = i0 + wave;

  int ml = lane < NPSd ? lane : NPSd-1;
  int mv = ts_mask[s*NPSd + ml];
  unsigned long long mb = __ballot(mv == 1 && lane < NPSd);
  int nv = __popcll(mb);
  float scale = (float)nv * 0.125f;   // ne / sqrt(A=64)
  bool rowv = (mb >> (unsigned)irow) & 1ULL;

  float4 vv = *(const float4*)&vvL[wave][lane<<2];
  float cr = crL[wave];

  float4 o4 = make_float4(0.f, 0.f, 0.f, 0.f);
  float den = 0.f;

  if (rowv && nv > 1) {
    // lane l = l-th set bit of mb (in-register compact list)
    unsigned long long m = mb;
    int k = lane, jbit = 0, pc;
    pc = __popcll(m & 0xFFFFFFFFull); if (k >= pc) { jbit += 32; k -= pc; m >>= 32; }
    pc = __popcll(m & 0xFFFFull);     if (k >= pc) { jbit += 16; k -= pc; m >>= 16; }
    pc = __popcll(m & 0xFFull);       if (k >= pc) { jbit += 8;  k -= pc; m >>= 8; }
    pc = __popcll(m & 0xFull);        if (k >= pc) { jbit += 4;  k -= pc; m >>= 4; }
    pc = __popcll(m & 0x3ull);        if (k >= pc) { jbit += 2;  k -= pc; m >>= 2; }
    pc = (int)(m & 1ull);             if (k >= pc) { jbit += 1; }

    const float* rb = spatial + (size_t)row*NPSd*Hd;
    int nc = (nv + 3) >> 2;           // chunks of 4 slots
    float4 A[4], B[4], C[4];
    int jA[4], jB[4], jC[4];

#define ISSUE(DST, JD, Ch)                                                  \
    { _Pragma("unroll")                                                     \
      for (int rr = 0; rr < 4; ++rr) {                                      \
        int slot = (Ch)*4 + rr;                                             \
        int ss = slot < nv ? slot : 0;                                      \
        int j = __shfl(jbit, ss);                                           \
        JD[rr] = slot < nv ? j : -1;                                        \
        DST[rr] = *(const float4*)(rb + (size_t)j*Hd + (lane << 2));        \
      }                                                                     \
      __builtin_amdgcn_sched_barrier(0); }

#define DO_CHUNK(CUR, JC2)                                                  \
    { _Pragma("unroll")                                                     \
      for (int rr = 0; rr < 4; ++rr) {                                      \
        int j = JC2[rr];                                                    \
        float4 a4 = CUR[rr];                                                \
        float pp = a4.x*vv.x + a4.y*vv.y + a4.z*vv.z + a4.w*vv.w;           \
        pp += __shfl_xor(pp, 1);                                            \
        pp += __shfl_xor(pp, 2);                                            \
        pp += __shfl_xor(pp, 4);                                            \
        pp += __shfl_xor(pp, 8);                                            \
        pp += __shfl_xor(pp, 16);                                           \
        pp += __shfl_xor(pp, 32);                                           \
        bool valid = (j >= 0) && (j != irow);                               \
        float nj = valid ? __expf((pp + cr) * scale) : 0.f;                 \
        den += nj;                                                          \
        o4.x += nj*a4.x; o4.y += nj*a4.y; o4.z += nj*a4.z; o4.w += nj*a4.w; \
      } }

    ISSUE(A, jA, 0);
    if (nc > 1) ISSUE(B, jB, 1);
    if (nc > 2) ISSUE(C, jC, 2);
    int cc = 0;
    while (true) {
      DO_CHUNK(A, jA); if (cc + 3 < nc) ISSUE(A, jA, cc + 3);
      ++cc; if (cc >= nc) break;
      DO_CHUNK(B, jB); if (cc + 3 < nc) ISSUE(B, jB, cc + 3);
      ++cc; if (cc >= nc) break;
      DO_CHUNK(C, jC); if (cc + 3 < nc) ISSUE(C, jC, cc + 3);
      ++cc; if (cc >= nc) break;
    }
#undef ISSUE
#undef DO_CHUNK
  }

  float inv = den > 0.f ? 1.f/den : 0.f;
  o4.x *= inv; o4.y *= inv; o4.z *= inv; o4.w *= inv;
  *(float4*)(out + (size_t)row*Hd + (lane<<2)) = o4;
}

// ---------------------------------------------------------------------------
extern "C" void kernel_launch(void* const* d_in, const int* in_sizes, int n_in,
                              void* d_out, int out_size, void* d_ws, size_t ws_size,
                              hipStream_t stream) {
  const float* spatial  = (const float*)d_in[0];
  const float* temporal = (const float*)d_in[1];
  const float* W1_w     = (const float*)d_in[2];
  const float* W1_b     = (const float*)d_in[3];
  const float* W2_w     = (const float*)d_in[4];
  const float* W2_b     = (const float*)d_in[5];
  const int*   ts_mask  = (const int*)d_in[6];
  float* out = (float*)d_out;

  fused_kernel<<<Nd/ROWS, 256, 0, stream>>>(spatial, temporal, W1_w, W1_b,
                                            W2_w, W2_b, ts_mask, out);
}